// Round 1
// baseline (9472.804 us; speedup 1.0000x reference)
//
#include <hip/hip_runtime.h>
#include <math.h>

#define V_TOT 60000
#define B_TOT 8
#define VPB 8           // vertices per block
#define NPTS 64         // points per block = VPB * B_TOT
#define AS 260          // activation row stride in floats (16B aligned, bank-friendly)

// LDS layout (floats)
#define OFF_ACTA   0
#define OFF_ACTB   16640
#define OFF_ENCV   33280
#define OFF_ENCOV  33904
#define OFF_FEAT   34072
#define OFF_VERT   34568
#define OFF_TMPL   34616
#define OFF_EXPR   34640
#define OFF_POSEW  34832
#define OFF_UNION  34896
#define SMEM_FLOATS 38992
#define SMEM_BYTES  (SMEM_FLOATS * 4)

struct Params {
  const float* vertices; const float* features;
  const float* ew0; const float* eb0; const float* ew1; const float* eb1;
  const float* ew2; const float* eb2; const float* ew3; const float* eb3;
  const float* ew4; const float* eb4; const float* ew5; const float* eb5;
  const float* tw0; const float* tb0; const float* tw1; const float* tb1;
  const float* tw2; const float* tb2; const float* tw3; const float* tb3;
  const float* pw0; const float* pb0; const float* pw1; const float* pb1;
  const float* pw2; const float* pb2; const float* pw3; const float* pb3;
  const float* torigin; const float* scale;
  float* out;
};

__device__ __forceinline__ float silu_f(float x) { return x / (1.f + __expf(-x)); }
__device__ __forceinline__ float sigm_f(float x) { return 1.f / (1.f + __expf(-x)); }

// Generic LDS->LDS dense layer. lane = point (0..63). Each wave owns NOUT/4
// output columns; j index is wave-uniform -> W/bias reads become s_loads.
// i blocked by 32: activations staged to registers once per j-tile block.
template<int NIN, int NOUT, bool ACT>
__device__ __forceinline__ void mlp_layer(const float* __restrict__ W,
                                          const float* __restrict__ bias,
                                          const float* sin_, float* sout,
                                          int lane, int wv)
{
  constexpr int JPW = NOUT / 4;              // per-wave output columns
  constexpr int JT = (JPW >= 16) ? 16 : JPW; // j-tile
  const float* inr = sin_ + lane * AS;
  const int jend = (wv + 1) * JPW;
  for (int jt = wv * JPW; jt < jend; jt += JT) {
    float acc[JT];
    #pragma unroll
    for (int k = 0; k < JT; k++) acc[k] = bias[jt + k];
    #pragma unroll 1
    for (int i0 = 0; i0 < NIN; i0 += 32) {
      float a[32];
      #pragma unroll
      for (int ii = 0; ii < 32; ii += 4)
        *(float4*)(a + ii) = *(const float4*)(inr + i0 + ii);
      #pragma unroll
      for (int k = 0; k < JT; k++) {
        const float* Wr = W + (size_t)(jt + k) * NIN + i0;
        #pragma unroll
        for (int ii = 0; ii < 32; ii++)
          acc[k] = fmaf(a[ii], Wr[ii], acc[k]);
      }
    }
    #pragma unroll
    for (int k = 0; k < JT; k++)
      sout[lane * AS + jt + k] = ACT ? silu_f(acc[k]) : acc[k];
  }
}

extern "C" __global__ __launch_bounds__(256, 1)
void nbs_kernel(Params P)
{
  extern __shared__ float sm[];
  float* actA  = sm + OFF_ACTA;
  float* actB  = sm + OFF_ACTB;
  float* encv  = sm + OFF_ENCV;   // [8][78]
  float* encov = sm + OFF_ENCOV;  // [8][21]
  float* feat  = sm + OFF_FEAT;   // [8][62]
  float* vert  = sm + OFF_VERT;   // [8][6]
  float* tmplv = sm + OFF_TMPL;   // [8][3]
  float* exprv = sm + OFF_EXPR;   // [64][3]
  float* posew = sm + OFF_POSEW;  // [64]
  float* uni   = sm + OFF_UNION;  // 4096 floats, phase-overlaid
  float* U   = uni;               // [8][256] layer0 per-vertex partial
  float* Fb  = uni + 2048;        // [8][256] layer0 per-batch partial (+bias)
  float* P0v = uni;               // [8][64]  pose l0 per-vertex (after U dead)
  float* Pf  = uni + 512;         // [8][64]  pose l0 per-batch (+bias)
  float* tA  = uni + 1024;        // [8][64]
  float* tB  = uni + 1536;        // [8][32]
  float* tC  = uni + 1792;        // [8][32]

  const int tid  = threadIdx.x;
  const int lane = tid & 63;
  const int wv   = __builtin_amdgcn_readfirstlane(tid >> 6);
  const int v0   = blockIdx.x * VPB;

  // ---- phase 1: stage vertices/features, positional encodings ----
  for (int idx = tid; idx < VPB * 6; idx += 256)
    vert[idx] = P.vertices[(size_t)v0 * 6 + idx];
  for (int idx = tid; idx < B_TOT * 62; idx += 256)
    feat[idx] = P.features[idx];
  __syncthreads();
  for (int idx = tid; idx < VPB * 78; idx += 256) {
    int v = idx / 78, e = idx - v * 78;
    float val;
    if (e < 6) val = vert[v * 6 + e];
    else {
      int r = e - 6, k = r / 12, q = r - k * 12;
      float x = vert[v * 6 + (q < 6 ? q : q - 6)] * (float)(1 << k);
      val = (q < 6) ? __sinf(x) : __cosf(x);
    }
    encv[v * 78 + e] = val;
  }
  for (int idx = tid; idx < VPB * 21; idx += 256) {
    int v = idx / 21, e = idx - v * 21;
    float val;
    if (e < 3) val = vert[v * 6 + e];
    else {
      int r = e - 3, k = r / 6, q = r - k * 6;
      float x = vert[v * 6 + (q < 3 ? q : q - 3)] * (float)(1 << k);
      val = (q < 3) ? __sinf(x) : __cosf(x);
    }
    encov[v * 21 + e] = val;
  }
  __syncthreads();

  // ---- phase 2: expr layer0 split partials ----
  {
    int v = tid >> 5;            // vertex for U / batch for Fb
    int j0 = (tid & 31) * 8;
    for (int k = 0; k < 8; k++) {
      int j = j0 + k;
      const float* Wr = P.ew0 + (size_t)j * 131;
      float accU = 0.f, accF = P.eb0[j];
      for (int i = 0; i < 78; i++) accU = fmaf(encv[v * 78 + i], Wr[i], accU);
      for (int i = 0; i < 53; i++) accF = fmaf(feat[v * 62 + i], Wr[78 + i], accF);
      U[v * 256 + j]  = accU;
      Fb[v * 256 + j] = accF;
    }
  }
  __syncthreads();

  // ---- phase 3: h0 = silu(U + Fb) -> actA.  point p = vl*8 + b ----
  {
    int p = tid >> 2, j0 = (tid & 3) * 64;
    int vl = p >> 3, b = p & 7;
    for (int j = j0; j < j0 + 64; j++)
      actA[p * AS + j] = silu_f(U[vl * 256 + j] + Fb[b * 256 + j]);
  }
  __syncthreads();

  // ---- expr layers 1..4 ----
  mlp_layer<256, 256, true>(P.ew1, P.eb1, actA, actB, lane, wv); __syncthreads();
  mlp_layer<256, 128, true>(P.ew2, P.eb2, actB, actA, lane, wv); __syncthreads();
  mlp_layer<128, 128, true>(P.ew3, P.eb3, actA, actB, lane, wv); __syncthreads();
  mlp_layer<128, 128, true>(P.ew4, P.eb4, actB, actA, lane, wv); __syncthreads();

  // ---- expr layer 5: 128 -> 3 (waves 0..2, one component each) ----
  if (wv < 3) {
    float acc = P.eb5[wv];
    const float* Wr = P.ew5 + wv * 128;
    const float* inr = actA + lane * AS;
    for (int i = 0; i < 128; i++) acc = fmaf(inr[i], Wr[i], acc);
    exprv[lane * 3 + wv] = acc;
  }
  __syncthreads();

  // ---- template MLP (per-vertex) + pose layer0 partials ----
  {
    int v = tid >> 5, j2 = (tid & 31) * 2;
    for (int k = 0; k < 2; k++) {
      int j = j2 + k;
      const float* Wr = P.tw0 + j * 21;
      float acc = P.tb0[j];
      for (int i = 0; i < 21; i++) acc = fmaf(encov[v * 21 + i], Wr[i], acc);
      tA[v * 64 + j] = silu_f(acc);
    }
    for (int k = 0; k < 2; k++) {
      int j = j2 + k;
      const float* Wr = P.pw0 + j * 27;
      float accV = 0.f, accF = P.pb0[j];
      for (int i = 0; i < 21; i++) accV = fmaf(encov[v * 21 + i], Wr[i], accV);
      for (int i = 0; i < 6; i++)  accF = fmaf(feat[v * 62 + 53 + i], Wr[21 + i], accF);
      P0v[v * 64 + j] = accV;
      Pf[v * 64 + j]  = accF;
    }
  }
  __syncthreads();
  {
    int v = tid >> 5, j = tid & 31;
    const float* Wr = P.tw1 + j * 64;
    float acc = P.tb1[j];
    for (int i = 0; i < 64; i++) acc = fmaf(tA[v * 64 + i], Wr[i], acc);
    tB[v * 32 + j] = silu_f(acc);
  }
  __syncthreads();
  {
    int v = tid >> 5, j = tid & 31;
    const float* Wr = P.tw2 + j * 32;
    float acc = P.tb2[j];
    for (int i = 0; i < 32; i++) acc = fmaf(tB[v * 32 + i], Wr[i], acc);
    tC[v * 32 + j] = silu_f(acc);
  }
  __syncthreads();
  if (tid < 24) {
    int v = tid / 3, c = tid - v * 3;
    const float* Wr = P.tw3 + c * 32;
    float acc = P.tb3[c];
    for (int i = 0; i < 32; i++) acc = fmaf(tC[v * 32 + i], Wr[i], acc);
    tmplv[v * 3 + c] = acc;
  }
  // pose h0 -> actA cols 0..63 (actA free: expr already extracted)
  {
    int p = tid >> 2, j0 = (tid & 3) * 16;
    int vl = p >> 3, b = p & 7;
    for (int j = j0; j < j0 + 16; j++)
      actA[p * AS + j] = silu_f(P0v[vl * 64 + j] + Pf[b * 64 + j]);
  }
  __syncthreads();

  // ---- pose layers ----
  mlp_layer<64, 32, true>(P.pw1, P.pb1, actA, actB, lane, wv); __syncthreads();
  mlp_layer<32, 32, true>(P.pw2, P.pb2, actB, actA, lane, wv); __syncthreads();
  if (tid < 64) {
    float acc = P.pb3[0];
    const float* inr = actA + tid * AS;
    for (int i = 0; i < 32; i++) acc = fmaf(inr[i], P.pw3[i], acc);
    posew[tid] = sigm_f(acc);
  }
  __syncthreads();

  // ---- final: rotation + transform + store ----
  if (tid < 64) {
    int p = tid, vl = p >> 3, b = p & 7;
    float ox = P.torigin[0] * 0.1f, oy = P.torigin[1] * 0.1f, oz = P.torigin[2] * 0.1f;
    float sc = P.scale[0];
    float ev0 = vert[vl * 6 + 0] + exprv[p * 3 + 0] + tmplv[vl * 3 + 0];
    float ev1 = vert[vl * 6 + 1] + exprv[p * 3 + 1] + tmplv[vl * 3 + 1];
    float ev2 = vert[vl * 6 + 2] + exprv[p * 3 + 2] + tmplv[vl * 3 + 2];
    float w = posew[p];
    float a0 = feat[b * 62 + 53] * w;
    float a1 = feat[b * 62 + 54] * w;
    float a2 = feat[b * 62 + 55] * w;
    float c1 = __cosf(a0), s1 = __sinf(a0);
    float c2 = __cosf(a1), s2 = __sinf(a1);
    float c3 = __cosf(a2), s3 = __sinf(a2);
    // R = Rx(a0) @ Ry(a1) @ Rz(a2)
    float R00 = c2 * c3,                 R01 = -c2 * s3,                R02 = s2;
    float R10 = c1 * s3 + s1 * s2 * c3,  R11 = c1 * c3 - s1 * s2 * s3,  R12 = -s1 * c2;
    float R20 = s1 * s3 - c1 * s2 * c3,  R21 = s1 * c3 + c1 * s2 * s3,  R22 = c1 * c2;
    float l0 = (ev0 - ox) * sc, l1 = (ev1 - oy) * sc, l2 = (ev2 - oz) * sc;
    float o0 = l0 * R00 + l1 * R10 + l2 * R20 + feat[b * 62 + 56] + ox;
    float o1 = l0 * R01 + l1 * R11 + l2 * R21 + feat[b * 62 + 57] + oy;
    float o2 = l0 * R02 + l1 * R12 + l2 * R22 + feat[b * 62 + 58] + oz;
    size_t o = ((size_t)b * V_TOT + (v0 + vl)) * 3;
    P.out[o + 0] = o0; P.out[o + 1] = o1; P.out[o + 2] = o2;
  }
}

extern "C" void kernel_launch(void* const* d_in, const int* in_sizes, int n_in,
                              void* d_out, int out_size, void* d_ws, size_t ws_size,
                              hipStream_t stream)
{
  (void)in_sizes; (void)n_in; (void)out_size; (void)d_ws; (void)ws_size;
  Params P;
  P.vertices = (const float*)d_in[0];  P.features = (const float*)d_in[1];
  P.ew0 = (const float*)d_in[2];   P.eb0 = (const float*)d_in[3];
  P.ew1 = (const float*)d_in[4];   P.eb1 = (const float*)d_in[5];
  P.ew2 = (const float*)d_in[6];   P.eb2 = (const float*)d_in[7];
  P.ew3 = (const float*)d_in[8];   P.eb3 = (const float*)d_in[9];
  P.ew4 = (const float*)d_in[10];  P.eb4 = (const float*)d_in[11];
  P.ew5 = (const float*)d_in[12];  P.eb5 = (const float*)d_in[13];
  P.tw0 = (const float*)d_in[14];  P.tb0 = (const float*)d_in[15];
  P.tw1 = (const float*)d_in[16];  P.tb1 = (const float*)d_in[17];
  P.tw2 = (const float*)d_in[18];  P.tb2 = (const float*)d_in[19];
  P.tw3 = (const float*)d_in[20];  P.tb3 = (const float*)d_in[21];
  P.pw0 = (const float*)d_in[22];  P.pb0 = (const float*)d_in[23];
  P.pw1 = (const float*)d_in[24];  P.pb1 = (const float*)d_in[25];
  P.pw2 = (const float*)d_in[26];  P.pb2 = (const float*)d_in[27];
  P.pw3 = (const float*)d_in[28];  P.pb3 = (const float*)d_in[29];
  P.torigin = (const float*)d_in[30];
  P.scale   = (const float*)d_in[31];
  P.out = (float*)d_out;

  (void)hipFuncSetAttribute((const void*)nbs_kernel,
                            hipFuncAttributeMaxDynamicSharedMemorySize, SMEM_BYTES);
  hipLaunchKernelGGL(nbs_kernel, dim3(V_TOT / VPB), dim3(256), SMEM_BYTES, stream, P);
}

// Round 2
// 1117.721 us; speedup vs baseline: 8.4751x; 8.4751x over previous
//
#include <hip/hip_runtime.h>
#include <math.h>

#define V_TOT 60000
#define VPB 8
#define NBLK (V_TOT / VPB)

typedef short  s16x8 __attribute__((ext_vector_type(8)));
typedef float  f32x4 __attribute__((ext_vector_type(4)));

// ---- workspace layout (ushort element offsets), bf16 zero-padded weights ----
#define WS_EW0U 0          // [256][96]   ew0 cols 0..77  (K pad 96)
#define WS_EW0F 24576      // [256][64]   ew0 cols 78..130 (K pad 64)
#define WS_EW1  40960      // [256][256]
#define WS_EW2  106496     // [128][256]
#define WS_EW3  139264     // [128][128]
#define WS_EW4  155648     // [128][128]
#define WS_PW1  172032     // [32][64]
#define WS_PW2  174080     // [32][32]
#define WS_END  175104     // 350208 bytes

// ---- LDS layout (byte offsets) ----
// actAb  [64][264] bf16 @ 0       (33792 B)
// actBb  [64][264] bf16 @ 33792   (33792 B)  (ph0b/ph1b/ph2b alias inside)
// encvb  [16][104] bf16 @ 67584   (3328 B)
// featb  [16][72]  bf16 @ 70912   (2304 B)
// f32 region @ 73216: U[2048] Fb[2048] encov[168] feat[496] vert[48] tmplv[24] exprv[192]
#define SMEM_BYTES 93312

struct Params {
  const float* vertices; const float* features;
  const float* eb0; const float* eb1; const float* eb2; const float* eb3;
  const float* eb4; const float* ew5; const float* eb5;
  const float* tw0; const float* tb0; const float* tw1; const float* tb1;
  const float* tw2; const float* tb2; const float* tw3; const float* tb3;
  const float* pw0; const float* pb0; const float* pb1; const float* pb2;
  const float* pw3; const float* pb3;
  const float* torigin; const float* scale;
  const ushort* wsb;
  float* out;
};

__device__ __forceinline__ float silu_f(float x) { return x / (1.f + __expf(-x)); }
__device__ __forceinline__ ushort f2bf(float f) {
  unsigned u = __float_as_uint(f);
  return (ushort)((u + 0x7fffu + ((u >> 16) & 1u)) >> 16);
}
__device__ __forceinline__ float bf2f(ushort h) { return __uint_as_float(((unsigned)h) << 16); }

// MODE 0: silu -> bf16 -> outb[row*OUTSTRIDE+col]
// MODE 1: raw f32 -> outf[row*OUTSTRIDE+col], rows < 8 only (layer-0 partials, M=8 padded to 16)
template<int NIN, int NOUT, int MTILES, int INSTRIDE, int OUTSTRIDE, int MODE>
__device__ __forceinline__ void mfma_layer(const ushort* __restrict__ Wb,
                                           const float* __restrict__ bias,
                                           const ushort* inb, ushort* outb, float* outf,
                                           int lane, int wv)
{
  constexpr int NT_TOT = NOUT / 16;
  constexpr int SLOTS  = (NT_TOT + 3) / 4;
  const int r16 = lane & 15, g = lane >> 4;
  f32x4 acc[SLOTS][MTILES];
  #pragma unroll
  for (int s = 0; s < SLOTS; s++) {
    const int nt = wv + s * 4;
    float bv = 0.f;
    if (nt < NT_TOT && bias) bv = bias[nt * 16 + r16];
    #pragma unroll
    for (int mt = 0; mt < MTILES; mt++) acc[s][mt] = (f32x4){bv, bv, bv, bv};
  }
  #pragma unroll
  for (int k0 = 0; k0 < NIN; k0 += 32) {
    s16x8 a[MTILES];
    #pragma unroll
    for (int mt = 0; mt < MTILES; mt++)
      a[mt] = *(const s16x8*)(inb + (mt * 16 + r16) * INSTRIDE + k0 + g * 8);
    #pragma unroll
    for (int s = 0; s < SLOTS; s++) {
      const int nt = wv + s * 4;
      if (nt < NT_TOT) {
        s16x8 b = *(const s16x8*)(Wb + (size_t)(nt * 16 + r16) * NIN + k0 + g * 8);
        #pragma unroll
        for (int mt = 0; mt < MTILES; mt++)
          acc[s][mt] = __builtin_amdgcn_mfma_f32_16x16x32_bf16(a[mt], b, acc[s][mt], 0, 0, 0);
      }
    }
  }
  #pragma unroll
  for (int s = 0; s < SLOTS; s++) {
    const int nt = wv + s * 4;
    if (nt < NT_TOT) {
      const int col = nt * 16 + r16;
      #pragma unroll
      for (int mt = 0; mt < MTILES; mt++) {
        #pragma unroll
        for (int r = 0; r < 4; r++) {
          const int row = mt * 16 + g * 4 + r;
          float v = acc[s][mt][r];
          if (MODE == 0) outb[row * OUTSTRIDE + col] = f2bf(silu_f(v));
          else if (row < 8) outf[row * OUTSTRIDE + col] = v;
        }
      }
    }
  }
}

__global__ void conv_w(const float* __restrict__ src, ushort* __restrict__ dst,
                       int R, int Cs, int off, int Ccopy, int Cd)
{
  int i = blockIdx.x * 256 + threadIdx.x;
  if (i >= R * Cd) return;
  int r = i / Cd, c = i - r * Cd;
  float v = (c < Ccopy) ? src[r * Cs + off + c] : 0.f;
  dst[i] = f2bf(v);
}

extern "C" __global__ __launch_bounds__(256, 1)
void nbs_kernel(Params P)
{
  extern __shared__ char sm[];
  ushort* actAb = (ushort*)sm;                    // [64][264]
  ushort* actBb = (ushort*)(sm + 33792);          // [64][264]
  ushort* ph0b  = actBb;                          // [64][72]  (alias, after h3 dead)
  ushort* ph1b  = actBb + 4608;                   // [64][56]
  ushort* ph2b  = actBb + 8192;                   // [64][56]
  ushort* encvb = (ushort*)(sm + 67584);          // [16][104]
  ushort* featb = (ushort*)(sm + 70912);          // [16][72]
  float*  U     = (float*)(sm + 73216);           // [8][256]
  float*  Fb    = U + 2048;                       // [8][256]
  float*  P0v   = U;                              // aliases (U dead after combine)
  float*  Pf    = U + 512;
  float*  tA    = U + 1024;                       // [8][64]
  float*  tB    = U + 1536;                       // [8][32]
  float*  tC    = U + 1792;                       // [8][32]
  float*  encov = Fb + 2048;                      // [8][21]
  float*  feat  = encov + 168;                    // [8][62]
  float*  vert  = feat + 496;                     // [8][6]
  float*  tmplv = vert + 48;                      // [8][3]
  float*  exprv = tmplv + 24;                     // [64][3]

  const int tid  = threadIdx.x;
  const int lane = tid & 63;
  const int wv   = __builtin_amdgcn_readfirstlane(tid >> 6);
  const int v0   = blockIdx.x * VPB;

  // ---- P0: stage ----
  for (int idx = tid; idx < VPB * 6; idx += 256)
    vert[idx] = P.vertices[(size_t)v0 * 6 + idx];
  for (int idx = tid; idx < 8 * 62; idx += 256)
    feat[idx] = P.features[idx];
  __syncthreads();

  // ---- P1: encodings (bf16 A-layout) ----
  for (int idx = tid; idx < 16 * 104; idx += 256) {
    int v = idx / 104, e = idx - v * 104;
    float val = 0.f;
    if (v < 8 && e < 78) {
      if (e < 6) val = vert[v * 6 + e];
      else {
        int r = e - 6, k = r / 12, q = r - k * 12;
        float x = vert[v * 6 + (q < 6 ? q : q - 6)] * (float)(1 << k);
        val = (q < 6) ? __sinf(x) : __cosf(x);
      }
    }
    encvb[idx] = f2bf(val);
  }
  for (int idx = tid; idx < 16 * 72; idx += 256) {
    int b = idx / 72, e = idx - b * 72;
    float val = (b < 8 && e < 53) ? feat[b * 62 + e] : 0.f;
    featb[idx] = f2bf(val);
  }
  for (int idx = tid; idx < 8 * 21; idx += 256) {
    int v = idx / 21, e = idx - v * 21;
    float val;
    if (e < 3) val = vert[v * 6 + e];
    else {
      int r = e - 3, k = r / 6, q = r - k * 6;
      float x = vert[v * 6 + (q < 3 ? q : q - 3)] * (float)(1 << k);
      val = (q < 3) ? __sinf(x) : __cosf(x);
    }
    encov[idx] = val;
  }
  __syncthreads();

  // ---- P2: layer0 partials via MFMA (M=8 padded 16) ----
  mfma_layer< 96, 256, 1, 104, 256, 1>(P.wsb + WS_EW0U, nullptr, encvb, nullptr, U,  lane, wv);
  mfma_layer< 64, 256, 1,  72, 256, 1>(P.wsb + WS_EW0F, P.eb0,   featb, nullptr, Fb, lane, wv);
  __syncthreads();

  // ---- P3: h0 = silu(U + F) -> actAb bf16 ----
  {
    int p = tid & 63, vl = p >> 3, b = p & 7, j0 = (tid >> 6) * 64;
    for (int jj = 0; jj < 64; jj++) {
      int j = j0 + jj;
      actAb[p * 264 + j] = f2bf(silu_f(U[vl * 256 + j] + Fb[b * 256 + j]));
    }
  }
  __syncthreads();

  // ---- P4..P7: expr L1..L4 ----
  mfma_layer<256, 256, 4, 264, 264, 0>(P.wsb + WS_EW1, P.eb1, actAb, actBb, nullptr, lane, wv);
  __syncthreads();
  mfma_layer<256, 128, 4, 264, 264, 0>(P.wsb + WS_EW2, P.eb2, actBb, actAb, nullptr, lane, wv);
  __syncthreads();
  mfma_layer<128, 128, 4, 264, 264, 0>(P.wsb + WS_EW3, P.eb3, actAb, actBb, nullptr, lane, wv);
  __syncthreads();
  mfma_layer<128, 128, 4, 264, 264, 0>(P.wsb + WS_EW4, P.eb4, actBb, actAb, nullptr, lane, wv);
  __syncthreads();

  // ---- P8: waves 0-2: expr L5 (VALU); wave 3: template t0 + pose L0 partials ----
  if (wv < 3) {
    float a0 = 0.f, a1 = 0.f, a2 = 0.f, a3 = P.eb5[wv];
    const ushort* inr = actAb + lane * 264;
    #pragma unroll
    for (int c = 0; c < 16; c += 4) {
      s16x8 h0v = *(const s16x8*)(inr + (c + 0) * 8);
      s16x8 h1v = *(const s16x8*)(inr + (c + 1) * 8);
      s16x8 h2v = *(const s16x8*)(inr + (c + 2) * 8);
      s16x8 h3v = *(const s16x8*)(inr + (c + 3) * 8);
      #pragma unroll
      for (int i = 0; i < 8; i++) {
        a0 = fmaf(bf2f((ushort)h0v[i]), P.ew5[wv * 128 + (c + 0) * 8 + i], a0);
        a1 = fmaf(bf2f((ushort)h1v[i]), P.ew5[wv * 128 + (c + 1) * 8 + i], a1);
        a2 = fmaf(bf2f((ushort)h2v[i]), P.ew5[wv * 128 + (c + 2) * 8 + i], a2);
        a3 = fmaf(bf2f((ushort)h3v[i]), P.ew5[wv * 128 + (c + 3) * 8 + i], a3);
      }
    }
    exprv[lane * 3 + wv] = (a0 + a1) + (a2 + a3);
  } else {
    int v = lane >> 3, j0 = (lane & 7) * 8;
    for (int k = 0; k < 8; k++) {
      int j = j0 + k;
      const float* Wr = P.tw0 + j * 21;
      float a = P.tb0[j];
      for (int i = 0; i < 21; i++) a = fmaf(encov[v * 21 + i], Wr[i], a);
      tA[v * 64 + j] = silu_f(a);
    }
    for (int k = 0; k < 8; k++) {
      int j = j0 + k;
      const float* Wr = P.pw0 + j * 27;
      float aV = 0.f, aF = P.pb0[j];
      for (int i = 0; i < 21; i++) aV = fmaf(encov[v * 21 + i], Wr[i], aV);
      for (int i = 0; i < 6;  i++) aF = fmaf(feat[v * 62 + 53 + i], Wr[21 + i], aF);
      P0v[v * 64 + j] = aV;
      Pf[v * 64 + j]  = aF;
    }
  }
  __syncthreads();

  // ---- P9: template t1 + pose h0 combine -> ph0b ----
  {
    int v = tid >> 5, j = tid & 31;
    const float* Wr = P.tw1 + j * 64;
    float a = P.tb1[j];
    for (int i = 0; i < 64; i++) a = fmaf(tA[v * 64 + i], Wr[i], a);
    tB[v * 32 + j] = silu_f(a);
  }
  {
    int p = tid & 63, j0 = (tid >> 6) * 16;
    for (int jj = 0; jj < 16; jj++) {
      int j = j0 + jj;
      ph0b[p * 72 + j] = f2bf(silu_f(P0v[(p >> 3) * 64 + j] + Pf[(p & 7) * 64 + j]));
    }
  }
  __syncthreads();

  // ---- P10: pose L1 (waves 0-1, MFMA) + template t2 (waves 2-3) ----
  mfma_layer<64, 32, 4, 72, 56, 0>(P.wsb + WS_PW1, P.pb1, ph0b, ph1b, nullptr, lane, wv);
  if (wv >= 2) {
    int t2id = tid - 128;
    int v = t2id >> 4, j2 = (t2id & 15) * 2;
    for (int k = 0; k < 2; k++) {
      int j = j2 + k;
      const float* Wr = P.tw2 + j * 32;
      float a = P.tb2[j];
      for (int i = 0; i < 32; i++) a = fmaf(tB[v * 32 + i], Wr[i], a);
      tC[v * 32 + j] = silu_f(a);
    }
  }
  __syncthreads();

  // ---- P11: pose L2 (waves 0-1, MFMA) + template t3 (wave 2) ----
  mfma_layer<32, 32, 4, 56, 56, 0>(P.wsb + WS_PW2, P.pb2, ph1b, ph2b, nullptr, lane, wv);
  if (wv == 2 && lane < 24) {
    int v = lane / 3, c = lane - v * 3;
    const float* Wr = P.tw3 + c * 32;
    float a = P.tb3[c];
    for (int i = 0; i < 32; i++) a = fmaf(tC[v * 32 + i], Wr[i], a);
    tmplv[v * 3 + c] = a;
  }
  __syncthreads();

  // ---- P12: pose L3 + final transform + store ----
  if (tid < 64) {
    int p = tid, vl = p >> 3, b = p & 7;
    float aw = P.pb3[0];
    const ushort* pr = ph2b + p * 56;
    #pragma unroll
    for (int c = 0; c < 4; c++) {
      s16x8 h = *(const s16x8*)(pr + c * 8);
      #pragma unroll
      for (int i = 0; i < 8; i++)
        aw = fmaf(bf2f((ushort)h[i]), P.pw3[c * 8 + i], aw);
    }
    float w = 1.f / (1.f + __expf(-aw));

    float ox = P.torigin[0] * 0.1f, oy = P.torigin[1] * 0.1f, oz = P.torigin[2] * 0.1f;
    float sc = P.scale[0];
    float ev0 = vert[vl * 6 + 0] + exprv[p * 3 + 0] + tmplv[vl * 3 + 0];
    float ev1 = vert[vl * 6 + 1] + exprv[p * 3 + 1] + tmplv[vl * 3 + 1];
    float ev2 = vert[vl * 6 + 2] + exprv[p * 3 + 2] + tmplv[vl * 3 + 2];
    float a0 = feat[b * 62 + 53] * w;
    float a1 = feat[b * 62 + 54] * w;
    float a2 = feat[b * 62 + 55] * w;
    float c1 = __cosf(a0), s1 = __sinf(a0);
    float c2 = __cosf(a1), s2 = __sinf(a1);
    float c3 = __cosf(a2), s3 = __sinf(a2);
    float R00 = c2 * c3,                R01 = -c2 * s3,                R02 = s2;
    float R10 = c1 * s3 + s1 * s2 * c3, R11 = c1 * c3 - s1 * s2 * s3,  R12 = -s1 * c2;
    float R20 = s1 * s3 - c1 * s2 * c3, R21 = s1 * c3 + c1 * s2 * s3,  R22 = c1 * c2;
    float l0 = (ev0 - ox) * sc, l1 = (ev1 - oy) * sc, l2 = (ev2 - oz) * sc;
    float o0 = l0 * R00 + l1 * R10 + l2 * R20 + feat[b * 62 + 56] + ox;
    float o1 = l0 * R01 + l1 * R11 + l2 * R21 + feat[b * 62 + 57] + oy;
    float o2 = l0 * R02 + l1 * R12 + l2 * R22 + feat[b * 62 + 58] + oz;
    size_t o = ((size_t)b * V_TOT + (v0 + vl)) * 3;
    P.out[o + 0] = o0; P.out[o + 1] = o1; P.out[o + 2] = o2;
  }
}

extern "C" void kernel_launch(void* const* d_in, const int* in_sizes, int n_in,
                              void* d_out, int out_size, void* d_ws, size_t ws_size,
                              hipStream_t stream)
{
  (void)in_sizes; (void)n_in; (void)out_size; (void)ws_size;
  const float* ew0 = (const float*)d_in[2];
  const float* ew1 = (const float*)d_in[4];
  const float* ew2 = (const float*)d_in[6];
  const float* ew3 = (const float*)d_in[8];
  const float* ew4 = (const float*)d_in[10];
  const float* pw1 = (const float*)d_in[24];
  const float* pw2 = (const float*)d_in[26];
  ushort* wsp = (ushort*)d_ws;

  auto L = [&](const float* s, int woff, int R, int Cs, int off, int Cc, int Cd) {
    int n = R * Cd;
    hipLaunchKernelGGL(conv_w, dim3((n + 255) / 256), dim3(256), 0, stream,
                       s, wsp + woff, R, Cs, off, Cc, Cd);
  };
  L(ew0, WS_EW0U, 256, 131,  0,  78,  96);
  L(ew0, WS_EW0F, 256, 131, 78,  53,  64);
  L(ew1, WS_EW1,  256, 256,  0, 256, 256);
  L(ew2, WS_EW2,  128, 256,  0, 256, 256);
  L(ew3, WS_EW3,  128, 128,  0, 128, 128);
  L(ew4, WS_EW4,  128, 128,  0, 128, 128);
  L(pw1, WS_PW1,   32,  64,  0,  64,  64);
  L(pw2, WS_PW2,   32,  32,  0,  32,  32);

  Params P;
  P.vertices = (const float*)d_in[0];  P.features = (const float*)d_in[1];
  P.eb0 = (const float*)d_in[3];
  P.eb1 = (const float*)d_in[5];
  P.eb2 = (const float*)d_in[7];
  P.eb3 = (const float*)d_in[9];
  P.eb4 = (const float*)d_in[11];
  P.ew5 = (const float*)d_in[12];  P.eb5 = (const float*)d_in[13];
  P.tw0 = (const float*)d_in[14];  P.tb0 = (const float*)d_in[15];
  P.tw1 = (const float*)d_in[16];  P.tb1 = (const float*)d_in[17];
  P.tw2 = (const float*)d_in[18];  P.tb2 = (const float*)d_in[19];
  P.tw3 = (const float*)d_in[20];  P.tb3 = (const float*)d_in[21];
  P.pw0 = (const float*)d_in[22];  P.pb0 = (const float*)d_in[23];
  P.pb1 = (const float*)d_in[25];
  P.pb2 = (const float*)d_in[27];
  P.pw3 = (const float*)d_in[28];  P.pb3 = (const float*)d_in[29];
  P.torigin = (const float*)d_in[30];
  P.scale   = (const float*)d_in[31];
  P.wsb = (const ushort*)wsp;
  P.out = (float*)d_out;

  (void)hipFuncSetAttribute((const void*)nbs_kernel,
                            hipFuncAttributeMaxDynamicSharedMemorySize, SMEM_BYTES);
  hipLaunchKernelGGL(nbs_kernel, dim3(NBLK), dim3(256), SMEM_BYTES, stream, P);
}

// Round 3
// 453.157 us; speedup vs baseline: 20.9040x; 2.4665x over previous
//
#include <hip/hip_runtime.h>
#include <math.h>

#define V_TOT 60000
#define VPB 8
#define NBLK (V_TOT / VPB)   // 7500

typedef short  s16x8 __attribute__((ext_vector_type(8)));
typedef float  f32x4 __attribute__((ext_vector_type(4)));

// ---- ws: tile-major bf16 weights (ushort offsets). Tile(nt,k) = 512 elems:
// elem[lane*8+i] = W[nt*16+(lane&15)][k*32+(lane>>4)*8+i]
#define WS_EW0 0        // NT16 KS5
#define WS_EW1 40960    // NT16 KS8
#define WS_EW2 106496   // NT8  KS8
#define WS_EW3 139264   // NT8  KS4
#define WS_EW4 155648   // NT8  KS4
#define WS_EW5 172032   // NT1  KS4
#define WS_PW0 174080   // NT4  KS1
#define WS_PW1 176128   // NT2  KS2
#define WS_PW2 178176   // NT2  KS1
#define WS_PW3 179200   // NT1  KS1
#define WS_TW0 179712   // NT4  KS1
#define WS_TW1 181760   // NT2  KS2
#define WS_TW2 183808   // NT2  KS1
#define WS_TW3 184832   // NT1  KS1

// ---- LDS byte offsets ----
#define L_ACTA 0        // [64][264] bf16
#define L_ACTB 33792    // [64][264] bf16 ; A0 [64][160] aliases; ph0/ph1/ph2 alias later
#define L_PH0  33792    // [64][72] bf16
#define L_PH1  43008    // [64][40] bf16
#define L_PH2  48128    // [64][40] bf16
#define L_A0P  67584    // [64][32] bf16
#define L_A0T  71680    // [16][32] bf16
#define L_TA   72704    // [16][72] bf16
#define L_TB   75008    // [16][40] bf16
#define L_TC   76288    // [16][40] bf16
#define L_FEAT 77568    // [8][62] f32
#define L_VERT 79552    // [8][6]  f32
#define L_EXPR 79744    // [64][3] f32
#define L_TMPL 80512    // [8][3]  f32
#define L_POSW 80608    // [64]    f32
#define SMEM_BYTES 80864

struct Params {
  const float* vertices; const float* features;
  const float* eb0; const float* eb1; const float* eb2; const float* eb3;
  const float* eb4; const float* eb5;
  const float* tb0; const float* tb1; const float* tb2; const float* tb3;
  const float* pb0; const float* pb1; const float* pb2; const float* pb3;
  const float* torigin; const float* scale;
  const ushort* wsb;
  float* out;
};

__device__ __forceinline__ float silu_f(float x) { return x / (1.f + __expf(-x)); }
__device__ __forceinline__ ushort f2bf(float f) {
  unsigned u = __float_as_uint(f);
  return (ushort)((u + 0x7fffu + ((u >> 16) & 1u)) >> 16);
}

// big layer: all 8 waves split N; each wave covers all 4 M-tiles.
template<int KS, int NT_TOT, int SLOTS, int INSTR, int OUTSTR>
__device__ __forceinline__ void big_layer(const ushort* __restrict__ Wt,
                                          const float* __restrict__ bias,
                                          const ushort* inb, ushort* outb,
                                          int lane, int wv)
{
  const int r16 = lane & 15, g = lane >> 4;
  f32x4 acc[SLOTS][4];
  #pragma unroll
  for (int s = 0; s < SLOTS; s++) {
    const int nt = wv + s * 8;
    float bv = bias[nt * 16 + r16];
    #pragma unroll
    for (int mt = 0; mt < 4; mt++) acc[s][mt] = (f32x4){bv, bv, bv, bv};
  }
  #pragma unroll
  for (int k = 0; k < KS; k++) {
    s16x8 a[4];
    #pragma unroll
    for (int mt = 0; mt < 4; mt++)
      a[mt] = *(const s16x8*)(inb + (mt * 16 + r16) * INSTR + k * 32 + g * 8);
    #pragma unroll
    for (int s = 0; s < SLOTS; s++) {
      const int nt = wv + s * 8;
      s16x8 b = *(const s16x8*)(Wt + (size_t)(nt * KS + k) * 512 + lane * 8);
      #pragma unroll
      for (int mt = 0; mt < 4; mt++)
        acc[s][mt] = __builtin_amdgcn_mfma_f32_16x16x32_bf16(a[mt], b, acc[s][mt], 0, 0, 0);
    }
  }
  #pragma unroll
  for (int s = 0; s < SLOTS; s++) {
    const int col = (wv + s * 8) * 16 + r16;
    #pragma unroll
    for (int mt = 0; mt < 4; mt++)
      #pragma unroll
      for (int r = 0; r < 4; r++)
        outb[(mt * 16 + g * 4 + r) * OUTSTR + col] = f2bf(silu_f(acc[s][mt][r]));
  }
}

// one 16x16 output tile
template<int KS, int INSTR>
__device__ __forceinline__ f32x4 tile_mm(const ushort* __restrict__ Wt,
                                         const ushort* inb, int mt, int lane, float bv)
{
  const int r16 = lane & 15, g = lane >> 4;
  f32x4 acc = (f32x4){bv, bv, bv, bv};
  #pragma unroll
  for (int k = 0; k < KS; k++) {
    s16x8 a = *(const s16x8*)(inb + (mt * 16 + r16) * INSTR + k * 32 + g * 8);
    s16x8 b = *(const s16x8*)(Wt + k * 512 + lane * 8);
    acc = __builtin_amdgcn_mfma_f32_16x16x32_bf16(a, b, acc, 0, 0, 0);
  }
  return acc;
}

__global__ void conv_w(const float* __restrict__ src, ushort* __restrict__ dst,
                       int NT, int KS, int Ksrc, int Kused, int Nused)
{
  int idx = blockIdx.x * 256 + threadIdx.x;
  if (idx >= NT * KS * 512) return;
  int t = idx >> 9, l = (idx >> 3) & 63, i = idx & 7;
  int nt = t / KS, k = t - nt * KS;
  int row = nt * 16 + (l & 15);
  int kk = k * 32 + (l >> 4) * 8 + i;
  float v = (row < Nused && kk < Kused) ? src[row * Ksrc + kk] : 0.f;
  dst[idx] = f2bf(v);
}

extern "C" __global__ __launch_bounds__(512, 4)
void nbs_kernel(Params P)
{
  extern __shared__ char sm[];
  ushort* actAb = (ushort*)(sm + L_ACTA);
  ushort* a0    = (ushort*)(sm + L_ACTB);
  ushort* actBb = (ushort*)(sm + L_ACTB);
  ushort* ph0b  = (ushort*)(sm + L_PH0);
  ushort* ph1b  = (ushort*)(sm + L_PH1);
  ushort* ph2b  = (ushort*)(sm + L_PH2);
  ushort* a0p   = (ushort*)(sm + L_A0P);
  ushort* a0t   = (ushort*)(sm + L_A0T);
  ushort* tAl   = (ushort*)(sm + L_TA);
  ushort* tBl   = (ushort*)(sm + L_TB);
  ushort* tCl   = (ushort*)(sm + L_TC);
  float*  featl = (float*)(sm + L_FEAT);
  float*  vertl = (float*)(sm + L_VERT);
  float*  exprv = (float*)(sm + L_EXPR);
  float*  tmplv = (float*)(sm + L_TMPL);
  float*  posew = (float*)(sm + L_POSW);

  const int tid  = threadIdx.x;
  const int lane = tid & 63;
  const int wv   = __builtin_amdgcn_readfirstlane(tid >> 6);
  const int r16  = lane & 15, g = lane >> 4;
  const int v0   = blockIdx.x * VPB;
  const ushort* ws = P.wsb;

  // ---- Ph0: stage + build A0 / A0p / A0t ----
  for (int idx = tid; idx < 8 * 62; idx += 512) featl[idx] = P.features[idx];
  for (int idx = tid; idx < VPB * 6; idx += 512) vertl[idx] = P.vertices[(size_t)v0 * 6 + idx];
  __syncthreads();
  for (int idx = tid; idx < 64 * 160; idx += 512) {
    int p = idx / 160, e = idx - p * 160, vl = p >> 3, b = p & 7;
    float val = 0.f;
    if (e < 6) val = vertl[vl * 6 + e];
    else if (e < 78) {
      int r = e - 6, k = r / 12, q = r - k * 12;
      float x = vertl[vl * 6 + (q < 6 ? q : q - 6)] * (float)(1 << k);
      val = (q < 6) ? __sinf(x) : __cosf(x);
    } else if (e < 131) val = featl[b * 62 + (e - 78)];
    a0[idx] = f2bf(val);
  }
  for (int idx = tid; idx < 64 * 32; idx += 512) {
    int p = idx >> 5, e = idx & 31, vl = p >> 3, b = p & 7;
    float val = 0.f;
    if (e < 3) val = vertl[vl * 6 + e];
    else if (e < 21) {
      int r = e - 3, k = r / 6, q = r - k * 6;
      float x = vertl[vl * 6 + (q < 3 ? q : q - 3)] * (float)(1 << k);
      val = (q < 3) ? __sinf(x) : __cosf(x);
    } else if (e < 27) val = featl[b * 62 + 53 + (e - 21)];
    a0p[idx] = f2bf(val);
  }
  for (int idx = tid; idx < 16 * 32; idx += 512) {
    int v = idx >> 5, e = idx & 31;
    float val = 0.f;
    if (v < 8) {
      if (e < 3) val = vertl[v * 6 + e];
      else if (e < 21) {
        int r = e - 3, k = r / 6, q = r - k * 6;
        float x = vertl[v * 6 + (q < 3 ? q : q - 3)] * (float)(1 << k);
        val = (q < 3) ? __sinf(x) : __cosf(x);
      }
    }
    a0t[idx] = f2bf(val);
  }
  __syncthreads();

  // ---- L0: A0[64][160] x EW0 -> actA ----
  big_layer<5, 16, 2, 160, 264>(ws + WS_EW0, P.eb0, a0, actAb, lane, wv);
  __syncthreads();
  // ---- L1..L4 ----
  big_layer<8, 16, 2, 264, 264>(ws + WS_EW1, P.eb1, actAb, actBb, lane, wv);
  __syncthreads();
  big_layer<8, 8, 1, 264, 264>(ws + WS_EW2, P.eb2, actBb, actAb, lane, wv);
  __syncthreads();
  big_layer<4, 8, 1, 264, 264>(ws + WS_EW3, P.eb3, actAb, actBb, lane, wv);
  __syncthreads();
  big_layer<4, 8, 1, 264, 264>(ws + WS_EW4, P.eb4, actBb, actAb, lane, wv);
  __syncthreads();

  // ---- T1: pose L0 (w0-3) | template t0 (w4-7) ----
  if (wv < 4) {
    const int nt = wv;
    float bv = P.pb0[nt * 16 + r16];
    #pragma unroll
    for (int mt = 0; mt < 4; mt++) {
      f32x4 d = tile_mm<1, 32>(ws + WS_PW0 + nt * 512, a0p, mt, lane, bv);
      #pragma unroll
      for (int r = 0; r < 4; r++)
        ph0b[(mt * 16 + g * 4 + r) * 72 + nt * 16 + r16] = f2bf(silu_f(d[r]));
    }
  } else {
    const int nt = wv - 4;
    float bv = P.tb0[nt * 16 + r16];
    f32x4 d = tile_mm<1, 32>(ws + WS_TW0 + nt * 512, a0t, 0, lane, bv);
    #pragma unroll
    for (int r = 0; r < 4; r++)
      tAl[(g * 4 + r) * 72 + nt * 16 + r16] = f2bf(silu_f(d[r]));
  }
  __syncthreads();

  // ---- T2: expr L5 (w4-7) | pose L1 (w0-1) | template t1 (w2-3) ----
  if (wv >= 4) {
    const int mt = wv - 4;
    float bv = (r16 < 3) ? P.eb5[r16] : 0.f;
    f32x4 d = tile_mm<4, 264>(ws + WS_EW5, actAb, mt, lane, bv);
    if (r16 < 3) {
      #pragma unroll
      for (int r = 0; r < 4; r++)
        exprv[(mt * 16 + g * 4 + r) * 3 + r16] = d[r];
    }
  } else if (wv < 2) {
    float bv = P.pb1[wv * 16 + r16];
    #pragma unroll
    for (int mt = 0; mt < 4; mt++) {
      f32x4 d = tile_mm<2, 72>(ws + WS_PW1 + wv * 2 * 512, ph0b, mt, lane, bv);
      #pragma unroll
      for (int r = 0; r < 4; r++)
        ph1b[(mt * 16 + g * 4 + r) * 40 + wv * 16 + r16] = f2bf(silu_f(d[r]));
    }
  } else {
    const int nt = wv - 2;
    float bv = P.tb1[nt * 16 + r16];
    f32x4 d = tile_mm<2, 72>(ws + WS_TW1 + nt * 2 * 512, tAl, 0, lane, bv);
    #pragma unroll
    for (int r = 0; r < 4; r++)
      tBl[(g * 4 + r) * 40 + nt * 16 + r16] = f2bf(silu_f(d[r]));
  }
  __syncthreads();

  // ---- T3: pose L2 (w0-1) | template t2 (w2) ----
  if (wv < 2) {
    float bv = P.pb2[wv * 16 + r16];
    #pragma unroll
    for (int mt = 0; mt < 4; mt++) {
      f32x4 d = tile_mm<1, 40>(ws + WS_PW2 + wv * 512, ph1b, mt, lane, bv);
      #pragma unroll
      for (int r = 0; r < 4; r++)
        ph2b[(mt * 16 + g * 4 + r) * 40 + wv * 16 + r16] = f2bf(silu_f(d[r]));
    }
  } else if (wv == 2) {
    #pragma unroll
    for (int nt = 0; nt < 2; nt++) {
      float bv = P.tb2[nt * 16 + r16];
      f32x4 d = tile_mm<1, 40>(ws + WS_TW2 + nt * 512, tBl, 0, lane, bv);
      #pragma unroll
      for (int r = 0; r < 4; r++)
        tCl[(g * 4 + r) * 40 + nt * 16 + r16] = f2bf(silu_f(d[r]));
    }
  }
  __syncthreads();

  // ---- T4: pose L3 -> sigmoid (w0) | template t3 (w1) ----
  if (wv == 0) {
    float bv = (r16 == 0) ? P.pb3[0] : 0.f;
    #pragma unroll
    for (int mt = 0; mt < 4; mt++) {
      f32x4 d = tile_mm<1, 40>(ws + WS_PW3, ph2b, mt, lane, bv);
      if (r16 == 0) {
        #pragma unroll
        for (int r = 0; r < 4; r++)
          posew[mt * 16 + g * 4 + r] = 1.f / (1.f + __expf(-d[r]));
      }
    }
  } else if (wv == 1) {
    float bv = (r16 < 3) ? P.tb3[r16] : 0.f;
    f32x4 d = tile_mm<1, 40>(ws + WS_TW3, tCl, 0, lane, bv);
    if (r16 < 3) {
      #pragma unroll
      for (int r = 0; r < 4; r++) {
        int row = g * 4 + r;
        if (row < 8) tmplv[row * 3 + r16] = d[r];
      }
    }
  }
  __syncthreads();

  // ---- final transform + store ----
  if (tid < 64) {
    int p = tid, vl = p >> 3, b = p & 7;
    float ox = P.torigin[0] * 0.1f, oy = P.torigin[1] * 0.1f, oz = P.torigin[2] * 0.1f;
    float sc = P.scale[0];
    float ev0 = vertl[vl * 6 + 0] + exprv[p * 3 + 0] + tmplv[vl * 3 + 0];
    float ev1 = vertl[vl * 6 + 1] + exprv[p * 3 + 1] + tmplv[vl * 3 + 1];
    float ev2 = vertl[vl * 6 + 2] + exprv[p * 3 + 2] + tmplv[vl * 3 + 2];
    float w = posew[p];
    float a0a = featl[b * 62 + 53] * w;
    float a1a = featl[b * 62 + 54] * w;
    float a2a = featl[b * 62 + 55] * w;
    float c1 = __cosf(a0a), s1 = __sinf(a0a);
    float c2 = __cosf(a1a), s2 = __sinf(a1a);
    float c3 = __cosf(a2a), s3 = __sinf(a2a);
    float R00 = c2 * c3,                R01 = -c2 * s3,                R02 = s2;
    float R10 = c1 * s3 + s1 * s2 * c3, R11 = c1 * c3 - s1 * s2 * s3,  R12 = -s1 * c2;
    float R20 = s1 * s3 - c1 * s2 * c3, R21 = s1 * c3 + c1 * s2 * s3,  R22 = c1 * c2;
    float l0 = (ev0 - ox) * sc, l1 = (ev1 - oy) * sc, l2 = (ev2 - oz) * sc;
    float o0 = l0 * R00 + l1 * R10 + l2 * R20 + featl[b * 62 + 56] + ox;
    float o1 = l0 * R01 + l1 * R11 + l2 * R21 + featl[b * 62 + 57] + oy;
    float o2 = l0 * R02 + l1 * R12 + l2 * R22 + featl[b * 62 + 58] + oz;
    size_t o = ((size_t)b * V_TOT + (v0 + vl)) * 3;
    P.out[o + 0] = o0; P.out[o + 1] = o1; P.out[o + 2] = o2;
  }
}

extern "C" void kernel_launch(void* const* d_in, const int* in_sizes, int n_in,
                              void* d_out, int out_size, void* d_ws, size_t ws_size,
                              hipStream_t stream)
{
  (void)in_sizes; (void)n_in; (void)out_size; (void)ws_size;
  ushort* wsp = (ushort*)d_ws;

  auto L = [&](const void* s, int woff, int NT, int KS, int Ksrc, int Kused, int Nused) {
    int n = NT * KS * 512;
    hipLaunchKernelGGL(conv_w, dim3((n + 255) / 256), dim3(256), 0, stream,
                       (const float*)s, wsp + woff, NT, KS, Ksrc, Kused, Nused);
  };
  L(d_in[2],  WS_EW0, 16, 5, 131, 131, 256);
  L(d_in[4],  WS_EW1, 16, 8, 256, 256, 256);
  L(d_in[6],  WS_EW2,  8, 8, 256, 256, 128);
  L(d_in[8],  WS_EW3,  8, 4, 128, 128, 128);
  L(d_in[10], WS_EW4,  8, 4, 128, 128, 128);
  L(d_in[12], WS_EW5,  1, 4, 128, 128, 3);
  L(d_in[22], WS_PW0,  4, 1,  27,  27, 64);
  L(d_in[24], WS_PW1,  2, 2,  64,  64, 32);
  L(d_in[26], WS_PW2,  2, 1,  32,  32, 32);
  L(d_in[28], WS_PW3,  1, 1,  32,  32, 1);
  L(d_in[14], WS_TW0,  4, 1,  21,  21, 64);
  L(d_in[16], WS_TW1,  2, 2,  64,  64, 32);
  L(d_in[18], WS_TW2,  2, 1,  32,  32, 32);
  L(d_in[20], WS_TW3,  1, 1,  32,  32, 3);

  Params P;
  P.vertices = (const float*)d_in[0];  P.features = (const float*)d_in[1];
  P.eb0 = (const float*)d_in[3];   P.eb1 = (const float*)d_in[5];
  P.eb2 = (const float*)d_in[7];   P.eb3 = (const float*)d_in[9];
  P.eb4 = (const float*)d_in[11];  P.eb5 = (const float*)d_in[13];
  P.tb0 = (const float*)d_in[15];  P.tb1 = (const float*)d_in[17];
  P.tb2 = (const float*)d_in[19];  P.tb3 = (const float*)d_in[21];
  P.pb0 = (const float*)d_in[23];  P.pb1 = (const float*)d_in[25];
  P.pb2 = (const float*)d_in[27];  P.pb3 = (const float*)d_in[29];
  P.torigin = (const float*)d_in[30];
  P.scale   = (const float*)d_in[31];
  P.wsb = (const ushort*)wsp;
  P.out = (float*)d_out;

  (void)hipFuncSetAttribute((const void*)nbs_kernel,
                            hipFuncAttributeMaxDynamicSharedMemorySize, SMEM_BYTES);
  hipLaunchKernelGGL(nbs_kernel, dim3(NBLK), dim3(512), SMEM_BYTES, stream, P);
}

// Round 4
// 320.448 us; speedup vs baseline: 29.5612x; 1.4141x over previous
//
#include <hip/hip_runtime.h>
#include <hip/hip_bf16.h>
#include <math.h>

#define V_TOT 60000
#define VPB 8
#define NBLK (V_TOT / VPB)   // 7500

typedef short  s16x8 __attribute__((ext_vector_type(8)));
typedef float  f32x4 __attribute__((ext_vector_type(4)));

// ---- ws: tile-major bf16 weights (ushort offsets). Tile(nt,k) = 512 elems:
// elem[lane*8+i] = W[nt*16+(lane&15)][k*32+(lane>>4)*8+i]   (A-frag layout)
#define WS_EW0 0        // NT16 KS5
#define WS_EW1 40960    // NT16 KS8
#define WS_EW2 106496   // NT8  KS8
#define WS_EW3 139264   // NT8  KS4
#define WS_EW4 155648   // NT8  KS4
#define WS_EW5 172032   // NT1  KS4
#define WS_PW0 174080   // NT4  KS1
#define WS_PW1 176128   // NT2  KS2
#define WS_PW2 178176   // NT2  KS1
#define WS_PW3 179200   // NT1  KS1
#define WS_TW0 179712   // NT4  KS1
#define WS_TW1 181760   // NT2  KS2
#define WS_TW2 183808   // NT2  KS1
#define WS_TW3 184832   // NT1  KS1

// ---- LDS byte offsets ----
#define L_ACTA 0        // [64][264] bf16 (encf/oencf alias here until L0 writes)
#define L_ENCF 0        // [8][80] f32  (alias in ACTA)
#define L_OENC 2560     // [8][24] f32  (alias in ACTA)
#define L_ACTB 33792    // [64][264] bf16 ; a0 [64][160] aliases; ph0/ph1/ph2 alias later
#define L_PH0  33792    // [64][72] bf16
#define L_PH1  43008    // [64][40] bf16
#define L_PH2  48128    // [64][40] bf16
#define L_A0P  67584    // [64][32] bf16
#define L_A0T  71680    // [16][32] bf16
#define L_TA   72704    // [16][72] bf16
#define L_TB   75008    // [16][40] bf16
#define L_TC   76288    // [16][40] bf16
#define L_FEAT 77568    // [8][62] f32
#define L_VERT 79552    // [8][6]  f32
#define L_EXPR 79744    // [64][3] f32
#define L_TMPL 80512    // [8][3]  f32
#define L_POSW 80608    // [64]    f32
#define SMEM_BYTES 80864   // <= 81920 -> 2 blocks/CU

struct Params {
  const float* vertices; const float* features;
  const float* eb0; const float* eb1; const float* eb2; const float* eb3;
  const float* eb4; const float* eb5;
  const float* tb0; const float* tb1; const float* tb2; const float* tb3;
  const float* pb0; const float* pb1; const float* pb2; const float* pb3;
  const float* torigin; const float* scale;
  const ushort* wsb;
  float* out;
};

// silu via v_exp + v_rcp (avoids the precise-division instruction chain)
__device__ __forceinline__ float silu_f(float x) {
  float e = __expf(-x);
  return x * __builtin_amdgcn_rcpf(1.f + e);
}
__device__ __forceinline__ float sigm_f(float x) {
  return __builtin_amdgcn_rcpf(1.f + __expf(-x));
}
__device__ __forceinline__ ushort f2bf(float f) {
  unsigned u = __float_as_uint(f);
  return (ushort)((u + 0x7fffu + ((u >> 16) & 1u)) >> 16);
}
// packed f32x2 -> bf16x2 (v_cvt_pk_bf16_f32)
__device__ __forceinline__ unsigned pack2bf(float a, float b) {
  __hip_bfloat162 h = __float22bfloat162_rn(float2{a, b});
  unsigned u; __builtin_memcpy(&u, &h, 4); return u;
}

// swapped big layer: weights = A-operand, activations = B-operand.
// D[feat][pt]: lane holds pt = lane&15, feats g*4..g*4+3 -> packed b64 epilogue.
template<int KS, int SLOTS, int INSTR, int OUTSTR>
__device__ __forceinline__ void big_layer_T(const ushort* __restrict__ Wt,
                                            const float* __restrict__ bias,
                                            const ushort* inb, ushort* outb,
                                            int lane, int wv)
{
  const int r16 = lane & 15, g = lane >> 4;
  f32x4 acc[SLOTS][4];
  #pragma unroll
  for (int s = 0; s < SLOTS; s++) {
    const int nt = wv + s * 8;
    const float4 bv = *(const float4*)(bias + nt * 16 + g * 4);
    #pragma unroll
    for (int mt = 0; mt < 4; mt++) acc[s][mt] = (f32x4){bv.x, bv.y, bv.z, bv.w};
  }
  #pragma unroll
  for (int k = 0; k < KS; k++) {
    s16x8 bf[4];
    #pragma unroll
    for (int mt = 0; mt < 4; mt++)
      bf[mt] = *(const s16x8*)(inb + (mt * 16 + r16) * INSTR + k * 32 + g * 8);
    #pragma unroll
    for (int s = 0; s < SLOTS; s++) {
      const int nt = wv + s * 8;
      s16x8 aw = *(const s16x8*)(Wt + (size_t)(nt * KS + k) * 512 + lane * 8);
      #pragma unroll
      for (int mt = 0; mt < 4; mt++)
        acc[s][mt] = __builtin_amdgcn_mfma_f32_16x16x32_bf16(aw, bf[mt], acc[s][mt], 0, 0, 0);
    }
  }
  #pragma unroll
  for (int s = 0; s < SLOTS; s++) {
    const int nt = wv + s * 8;
    #pragma unroll
    for (int mt = 0; mt < 4; mt++) {
      uint2 w;
      w.x = pack2bf(silu_f(acc[s][mt][0]), silu_f(acc[s][mt][1]));
      w.y = pack2bf(silu_f(acc[s][mt][2]), silu_f(acc[s][mt][3]));
      *(uint2*)(outb + (mt * 16 + r16) * OUTSTR + nt * 16 + g * 4) = w;
    }
  }
}

// one swapped 16x16 tile: D[feat][pt]
template<int KS, int INSTR>
__device__ __forceinline__ f32x4 tile_mm_T(const ushort* __restrict__ Wt,
                                           const ushort* inb, int mt, int lane, f32x4 binit)
{
  const int r16 = lane & 15, g = lane >> 4;
  f32x4 acc = binit;
  #pragma unroll
  for (int k = 0; k < KS; k++) {
    s16x8 aw = *(const s16x8*)(Wt + k * 512 + lane * 8);
    s16x8 bf = *(const s16x8*)(inb + (mt * 16 + r16) * INSTR + k * 32 + g * 8);
    acc = __builtin_amdgcn_mfma_f32_16x16x32_bf16(aw, bf, acc, 0, 0, 0);
  }
  return acc;
}

__global__ void conv_w(const float* __restrict__ src, ushort* __restrict__ dst,
                       int NT, int KS, int Ksrc, int Kused, int Nused)
{
  int idx = blockIdx.x * 256 + threadIdx.x;
  if (idx >= NT * KS * 512) return;
  int t = idx >> 9, l = (idx >> 3) & 63, i = idx & 7;
  int nt = t / KS, k = t - nt * KS;
  int row = nt * 16 + (l & 15);
  int kk = k * 32 + (l >> 4) * 8 + i;
  float v = (row < Nused && kk < Kused) ? src[row * Ksrc + kk] : 0.f;
  dst[idx] = f2bf(v);
}

extern "C" __global__ __launch_bounds__(512, 4)
void nbs_kernel(Params P)
{
  extern __shared__ char sm[];
  ushort* actAb = (ushort*)(sm + L_ACTA);
  float*  encf  = (float*)(sm + L_ENCF);
  float*  oencf = (float*)(sm + L_OENC);
  ushort* a0    = (ushort*)(sm + L_ACTB);
  ushort* actBb = (ushort*)(sm + L_ACTB);
  ushort* ph0b  = (ushort*)(sm + L_PH0);
  ushort* ph1b  = (ushort*)(sm + L_PH1);
  ushort* ph2b  = (ushort*)(sm + L_PH2);
  ushort* a0p   = (ushort*)(sm + L_A0P);
  ushort* a0t   = (ushort*)(sm + L_A0T);
  ushort* tAl   = (ushort*)(sm + L_TA);
  ushort* tBl   = (ushort*)(sm + L_TB);
  ushort* tCl   = (ushort*)(sm + L_TC);
  float*  featl = (float*)(sm + L_FEAT);
  float*  vertl = (float*)(sm + L_VERT);
  float*  exprv = (float*)(sm + L_EXPR);
  float*  tmplv = (float*)(sm + L_TMPL);
  float*  posew = (float*)(sm + L_POSW);

  const int tid  = threadIdx.x;
  const int lane = tid & 63;
  const int wv   = __builtin_amdgcn_readfirstlane(tid >> 6);
  const int r16  = lane & 15, g = lane >> 4;
  const int v0   = blockIdx.x * VPB;
  const ushort* ws = P.wsb;

  // ---- P0: stage inputs ----
  for (int idx = tid; idx < 8 * 62; idx += 512) featl[idx] = P.features[idx];
  for (int idx = tid; idx < VPB * 6; idx += 512) vertl[idx] = P.vertices[(size_t)v0 * 6 + idx];
  __syncthreads();

  // ---- P1: per-vertex encodings, once (f32) ----
  for (int idx = tid; idx < 8 * 80; idx += 512) {
    int v = idx / 80, e = idx - v * 80;
    float val = 0.f;
    if (e < 6) val = vertl[v * 6 + e];
    else if (e < 78) {
      int r = e - 6, k = r / 12, q = r - k * 12;
      float x = vertl[v * 6 + (q < 6 ? q : q - 6)] * (float)(1 << k);
      val = (q < 6) ? __sinf(x) : __cosf(x);
    }
    encf[idx] = val;
  }
  for (int idx = tid; idx < 8 * 24; idx += 512) {
    int v = idx / 24, e = idx - v * 24;
    float val = 0.f;
    if (e < 3) val = vertl[v * 6 + e];
    else if (e < 21) {
      int r = e - 3, k = r / 6, q = r - k * 6;
      float x = vertl[v * 6 + (q < 3 ? q : q - 3)] * (float)(1 << k);
      val = (q < 3) ? __sinf(x) : __cosf(x);
    }
    oencf[idx] = val;
  }
  __syncthreads();

  // ---- P2: build bf16 inputs via packed pair copies ----
  {
    uint* a0u = (uint*)a0;
    for (int idx = tid; idx < 64 * 80; idx += 512) {
      int p = idx / 80, q = idx - p * 80, vl = p >> 3, b = p & 7;
      int e0 = q * 2, e1 = e0 + 1;
      float s0 = (e0 < 78) ? encf[vl * 80 + e0] : (e0 < 131 ? featl[b * 62 + e0 - 78] : 0.f);
      float s1 = (e1 < 78) ? encf[vl * 80 + e1] : (e1 < 131 ? featl[b * 62 + e1 - 78] : 0.f);
      a0u[p * 80 + q] = pack2bf(s0, s1);
    }
    uint* a0pu = (uint*)a0p;
    for (int idx = tid; idx < 64 * 16; idx += 512) {
      int p = idx >> 4, q = idx & 15, vl = p >> 3, b = p & 7;
      int e0 = q * 2, e1 = e0 + 1;
      float s0 = (e0 < 21) ? oencf[vl * 24 + e0] : (e0 < 27 ? featl[b * 62 + 53 + e0 - 21] : 0.f);
      float s1 = (e1 < 21) ? oencf[vl * 24 + e1] : (e1 < 27 ? featl[b * 62 + 53 + e1 - 21] : 0.f);
      a0pu[p * 16 + q] = pack2bf(s0, s1);
    }
    uint* a0tu = (uint*)a0t;
    for (int idx = tid; idx < 16 * 16; idx += 512) {
      int v = idx >> 4, q = idx & 15;
      int e0 = q * 2, e1 = e0 + 1;
      float s0 = (v < 8 && e0 < 21) ? oencf[v * 24 + e0] : 0.f;
      float s1 = (v < 8 && e1 < 21) ? oencf[v * 24 + e1] : 0.f;
      a0tu[v * 16 + q] = pack2bf(s0, s1);
    }
  }
  __syncthreads();

  // ---- L0..L4 (expr MLP) ----
  big_layer_T<5, 2, 160, 264>(ws + WS_EW0, P.eb0, a0,    actAb, lane, wv);
  __syncthreads();
  big_layer_T<8, 2, 264, 264>(ws + WS_EW1, P.eb1, actAb, actBb, lane, wv);
  __syncthreads();
  big_layer_T<8, 1, 264, 264>(ws + WS_EW2, P.eb2, actBb, actAb, lane, wv);
  __syncthreads();
  big_layer_T<4, 1, 264, 264>(ws + WS_EW3, P.eb3, actAb, actBb, lane, wv);
  __syncthreads();
  big_layer_T<4, 1, 264, 264>(ws + WS_EW4, P.eb4, actBb, actAb, lane, wv);
  __syncthreads();

  // ---- T1: pose L0 (w0-3) | template t0 (w4-7) ----
  if (wv < 4) {
    const int nt = wv;
    const float4 bv = *(const float4*)(P.pb0 + nt * 16 + g * 4);
    #pragma unroll
    for (int mt = 0; mt < 4; mt++) {
      f32x4 d = tile_mm_T<1, 32>(ws + WS_PW0 + nt * 512, a0p, mt, lane,
                                 (f32x4){bv.x, bv.y, bv.z, bv.w});
      uint2 w;
      w.x = pack2bf(silu_f(d[0]), silu_f(d[1]));
      w.y = pack2bf(silu_f(d[2]), silu_f(d[3]));
      *(uint2*)(ph0b + (mt * 16 + r16) * 72 + nt * 16 + g * 4) = w;
    }
  } else {
    const int nt = wv - 4;
    const float4 bv = *(const float4*)(P.tb0 + nt * 16 + g * 4);
    f32x4 d = tile_mm_T<1, 32>(ws + WS_TW0 + nt * 512, a0t, 0, lane,
                               (f32x4){bv.x, bv.y, bv.z, bv.w});
    uint2 w;
    w.x = pack2bf(silu_f(d[0]), silu_f(d[1]));
    w.y = pack2bf(silu_f(d[2]), silu_f(d[3]));
    *(uint2*)(tAl + r16 * 72 + nt * 16 + g * 4) = w;
  }
  __syncthreads();

  // ---- T2: expr L5 (w4-7) | pose L1 (w0-1) | template t1 (w2-3) ----
  if (wv >= 4) {
    const int mt = wv - 4;
    f32x4 bi = (f32x4){0.f, 0.f, 0.f, 0.f};
    if (g == 0) bi = (f32x4){P.eb5[0], P.eb5[1], P.eb5[2], 0.f};
    f32x4 d = tile_mm_T<4, 264>(ws + WS_EW5, actAb, mt, lane, bi);
    if (g == 0) {
      exprv[(mt * 16 + r16) * 3 + 0] = d[0];
      exprv[(mt * 16 + r16) * 3 + 1] = d[1];
      exprv[(mt * 16 + r16) * 3 + 2] = d[2];
    }
  } else if (wv < 2) {
    const int nt = wv;
    const float4 bv = *(const float4*)(P.pb1 + nt * 16 + g * 4);
    #pragma unroll
    for (int mt = 0; mt < 4; mt++) {
      f32x4 d = tile_mm_T<2, 72>(ws + WS_PW1 + nt * 2 * 512, ph0b, mt, lane,
                                 (f32x4){bv.x, bv.y, bv.z, bv.w});
      uint2 w;
      w.x = pack2bf(silu_f(d[0]), silu_f(d[1]));
      w.y = pack2bf(silu_f(d[2]), silu_f(d[3]));
      *(uint2*)(ph1b + (mt * 16 + r16) * 40 + nt * 16 + g * 4) = w;
    }
  } else {
    const int nt = wv - 2;
    const float4 bv = *(const float4*)(P.tb1 + nt * 16 + g * 4);
    f32x4 d = tile_mm_T<2, 72>(ws + WS_TW1 + nt * 2 * 512, tAl, 0, lane,
                               (f32x4){bv.x, bv.y, bv.z, bv.w});
    uint2 w;
    w.x = pack2bf(silu_f(d[0]), silu_f(d[1]));
    w.y = pack2bf(silu_f(d[2]), silu_f(d[3]));
    *(uint2*)(tBl + r16 * 40 + nt * 16 + g * 4) = w;
  }
  __syncthreads();

  // ---- T3: pose L2 (w0-1) | template t2 (w2) ----
  if (wv < 2) {
    const int nt = wv;
    const float4 bv = *(const float4*)(P.pb2 + nt * 16 + g * 4);
    #pragma unroll
    for (int mt = 0; mt < 4; mt++) {
      f32x4 d = tile_mm_T<1, 40>(ws + WS_PW2 + nt * 512, ph1b, mt, lane,
                                 (f32x4){bv.x, bv.y, bv.z, bv.w});
      uint2 w;
      w.x = pack2bf(silu_f(d[0]), silu_f(d[1]));
      w.y = pack2bf(silu_f(d[2]), silu_f(d[3]));
      *(uint2*)(ph2b + (mt * 16 + r16) * 40 + nt * 16 + g * 4) = w;
    }
  } else if (wv == 2) {
    #pragma unroll
    for (int nt = 0; nt < 2; nt++) {
      const float4 bv = *(const float4*)(P.tb2 + nt * 16 + g * 4);
      f32x4 d = tile_mm_T<1, 40>(ws + WS_TW2 + nt * 512, tBl, 0, lane,
                                 (f32x4){bv.x, bv.y, bv.z, bv.w});
      uint2 w;
      w.x = pack2bf(silu_f(d[0]), silu_f(d[1]));
      w.y = pack2bf(silu_f(d[2]), silu_f(d[3]));
      *(uint2*)(tCl + r16 * 40 + nt * 16 + g * 4) = w;
    }
  }
  __syncthreads();

  // ---- T4: pose L3 -> sigmoid (w0) | template t3 (w1) ----
  if (wv == 0) {
    f32x4 bi = (g == 0) ? (f32x4){P.pb3[0], 0.f, 0.f, 0.f} : (f32x4){0.f, 0.f, 0.f, 0.f};
    #pragma unroll
    for (int mt = 0; mt < 4; mt++) {
      f32x4 d = tile_mm_T<1, 40>(ws + WS_PW3, ph2b, mt, lane, bi);
      if (g == 0) posew[mt * 16 + r16] = sigm_f(d[0]);
    }
  } else if (wv == 1) {
    f32x4 bi = (g == 0) ? (f32x4){P.tb3[0], P.tb3[1], P.tb3[2], 0.f}
                        : (f32x4){0.f, 0.f, 0.f, 0.f};
    f32x4 d = tile_mm_T<1, 40>(ws + WS_TW3, tCl, 0, lane, bi);
    if (g == 0 && r16 < 8) {
      tmplv[r16 * 3 + 0] = d[0];
      tmplv[r16 * 3 + 1] = d[1];
      tmplv[r16 * 3 + 2] = d[2];
    }
  }
  __syncthreads();

  // ---- final transform + store ----
  if (tid < 64) {
    int p = tid, vl = p >> 3, b = p & 7;
    float ox = P.torigin[0] * 0.1f, oy = P.torigin[1] * 0.1f, oz = P.torigin[2] * 0.1f;
    float sc = P.scale[0];
    float ev0 = vertl[vl * 6 + 0] + exprv[p * 3 + 0] + tmplv[vl * 3 + 0];
    float ev1 = vertl[vl * 6 + 1] + exprv[p * 3 + 1] + tmplv[vl * 3 + 1];
    float ev2 = vertl[vl * 6 + 2] + exprv[p * 3 + 2] + tmplv[vl * 3 + 2];
    float w = posew[p];
    float a0a = featl[b * 62 + 53] * w;
    float a1a = featl[b * 62 + 54] * w;
    float a2a = featl[b * 62 + 55] * w;
    float c1 = __cosf(a0a), s1 = __sinf(a0a);
    float c2 = __cosf(a1a), s2 = __sinf(a1a);
    float c3 = __cosf(a2a), s3 = __sinf(a2a);
    float R00 = c2 * c3,                R01 = -c2 * s3,                R02 = s2;
    float R10 = c1 * s3 + s1 * s2 * c3, R11 = c1 * c3 - s1 * s2 * s3,  R12 = -s1 * c2;
    float R20 = s1 * s3 - c1 * s2 * c3, R21 = s1 * c3 + c1 * s2 * s3,  R22 = c1 * c2;
    float l0 = (ev0 - ox) * sc, l1 = (ev1 - oy) * sc, l2 = (ev2 - oz) * sc;
    float o0 = l0 * R00 + l1 * R10 + l2 * R20 + featl[b * 62 + 56] + ox;
    float o1 = l0 * R01 + l1 * R11 + l2 * R21 + featl[b * 62 + 57] + oy;
    float o2 = l0 * R02 + l1 * R12 + l2 * R22 + featl[b * 62 + 58] + oz;
    size_t o = ((size_t)b * V_TOT + (v0 + vl)) * 3;
    P.out[o + 0] = o0; P.out[o + 1] = o1; P.out[o + 2] = o2;
  }
}

extern "C" void kernel_launch(void* const* d_in, const int* in_sizes, int n_in,
                              void* d_out, int out_size, void* d_ws, size_t ws_size,
                              hipStream_t stream)
{
  (void)in_sizes; (void)n_in; (void)out_size; (void)ws_size;
  ushort* wsp = (ushort*)d_ws;

  auto L = [&](const void* s, int woff, int NT, int KS, int Ksrc, int Kused, int Nused) {
    int n = NT * KS * 512;
    hipLaunchKernelGGL(conv_w, dim3((n + 255) / 256), dim3(256), 0, stream,
                       (const float*)s, wsp + woff, NT, KS, Ksrc, Kused, Nused);
  };
  L(d_in[2],  WS_EW0, 16, 5, 131, 131, 256);
  L(d_in[4],  WS_EW1, 16, 8, 256, 256, 256);
  L(d_in[6],  WS_EW2,  8, 8, 256, 256, 128);
  L(d_in[8],  WS_EW3,  8, 4, 128, 128, 128);
  L(d_in[10], WS_EW4,  8, 4, 128, 128, 128);
  L(d_in[12], WS_EW5,  1, 4, 128, 128, 3);
  L(d_in[22], WS_PW0,  4, 1,  27,  27, 64);
  L(d_in[24], WS_PW1,  2, 2,  64,  64, 32);
  L(d_in[26], WS_PW2,  2, 1,  32,  32, 32);
  L(d_in[28], WS_PW3,  1, 1,  32,  32, 1);
  L(d_in[14], WS_TW0,  4, 1,  21,  21, 64);
  L(d_in[16], WS_TW1,  2, 2,  64,  64, 32);
  L(d_in[18], WS_TW2,  2, 1,  32,  32, 32);
  L(d_in[20], WS_TW3,  1, 1,  32,  32, 3);

  Params P;
  P.vertices = (const float*)d_in[0];  P.features = (const float*)d_in[1];
  P.eb0 = (const float*)d_in[3];   P.eb1 = (const float*)d_in[5];
  P.eb2 = (const float*)d_in[7];   P.eb3 = (const float*)d_in[9];
  P.eb4 = (const float*)d_in[11];  P.eb5 = (const float*)d_in[13];
  P.tb0 = (const float*)d_in[15];  P.tb1 = (const float*)d_in[17];
  P.tb2 = (const float*)d_in[19];  P.tb3 = (const float*)d_in[21];
  P.pb0 = (const float*)d_in[23];  P.pb1 = (const float*)d_in[25];
  P.pb2 = (const float*)d_in[27];  P.pb3 = (const float*)d_in[29];
  P.torigin = (const float*)d_in[30];
  P.scale   = (const float*)d_in[31];
  P.wsb = (const ushort*)wsp;
  P.out = (float*)d_out;

  (void)hipFuncSetAttribute((const void*)nbs_kernel,
                            hipFuncAttributeMaxDynamicSharedMemorySize, SMEM_BYTES);
  hipLaunchKernelGGL(nbs_kernel, dim3(NBLK), dim3(512), SMEM_BYTES, stream, P);
}